// Round 3
// baseline (575.342 us; speedup 1.0000x reference)
//
#include <hip/hip_runtime.h>
#include <math.h>

// Problem constants
#define NB   8      // batch
#define HH   256
#define WW   256
#define CY   8      // y channels
#define HO   128
#define WO   128
#define OCN  512    // dcn output channels
#define K2   9
#define KJ   72     // 8*9 reduction length

// ---------------- Kernel A: y = leaky(conv1x1(x) + b), stored NHWC(8) ----------------
__global__ __launch_bounds__(256) void k_conv1(const float* __restrict__ x,
                                               const float* __restrict__ w,
                                               const float* __restrict__ b,
                                               float* __restrict__ y) {
    int idx = blockIdx.x * 256 + threadIdx.x;      // n*65536 + h*256 + w
    int n = idx >> 16, hw = idx & 65535;
    const float* xp = x + (size_t)n * 3 * 65536 + hw;
    float x0 = xp[0], x1 = xp[65536], x2 = xp[131072];
    float o[8];
#pragma unroll
    for (int oc = 0; oc < 8; ++oc) {
        float v = fmaf(w[oc*3+0], x0, fmaf(w[oc*3+1], x1, fmaf(w[oc*3+2], x2, b[oc])));
        o[oc] = v >= 0.f ? v : 0.1f * v;
    }
    float* yp = y + (size_t)idx * 8;
    *(float4*)(yp + 0) = make_float4(o[0], o[1], o[2], o[3]);
    *(float4*)(yp + 4) = make_float4(o[4], o[5], o[6], o[7]);
}

// ---- Kernel B: offset conv (27ch, 3x3, stride2, pad1) + sigmoid mask + bilinear sample ----
// Writes cols[pix][j], j = c*9 + k  (matches dcn_w flat layout [o][c][kh][kw])
__global__ __launch_bounds__(256) void k_offset_sample(const float* __restrict__ y,
                                                       const float* __restrict__ ow,
                                                       const float* __restrict__ ob,
                                                       float* __restrict__ cols) {
    __shared__ float wT[9 * 216];   // wT[pos][oc][c], c contiguous for float4 reads
    __shared__ float bS[27];
    int t = threadIdx.x;
    for (int i = t; i < 1944; i += 256) {
        int oc = i / 72, rem = i - oc * 72;
        int c = rem / 9, pos = rem - c * 9;
        wT[pos * 216 + oc * 8 + c] = ow[i];
    }
    if (t < 27) bS[t] = ob[t];
    __syncthreads();

    int idx = blockIdx.x * 256 + t;                // n*16384 + ho*128 + wo
    int n = idx >> 14, hw = idx & 16383;
    int ho = hw >> 7, wo = hw & 127;
    const float* yn = y + (size_t)n * (HH * WW * CY);

    float acc[27];
#pragma unroll
    for (int oc = 0; oc < 27; ++oc) acc[oc] = bS[oc];

#pragma unroll
    for (int pos = 0; pos < 9; ++pos) {
        int kh = pos / 3, kw = pos - kh * 3;
        int hi = 2 * ho - 1 + kh, wi = 2 * wo - 1 + kw;
        if ((unsigned)hi < 256u && (unsigned)wi < 256u) {
            const float* yp = yn + ((size_t)hi * 256 + wi) * 8;
            float4 a  = *(const float4*)(yp + 0);
            float4 c4 = *(const float4*)(yp + 4);
#pragma unroll
            for (int oc = 0; oc < 27; ++oc) {
                float4 w0 = *(const float4*)(wT + pos * 216 + oc * 8 + 0);
                float4 w1 = *(const float4*)(wT + pos * 216 + oc * 8 + 4);
                acc[oc] += w0.x * a.x + w0.y * a.y + w0.z * a.z + w0.w * a.w
                         + w1.x * c4.x + w1.y * c4.y + w1.z * c4.z + w1.w * c4.w;
            }
        }
    }

    float* cp = cols + (size_t)idx * KJ;
#pragma unroll
    for (int k = 0; k < 9; ++k) {
        float dy = acc[2 * k], dx = acc[2 * k + 1];
        float m  = 1.f / (1.f + expf(-acc[18 + k]));
        float py = (float)(2 * ho - 1 + (k / 3)) + dy;
        float px = (float)(2 * wo - 1 + (k % 3)) + dx;
        float y0f = floorf(py), x0f = floorf(px);
        float fy = py - y0f, fx = px - x0f;
        int y0 = (int)y0f, x0 = (int)x0f;
        float s0=0,s1=0,s2=0,s3=0,s4=0,s5=0,s6=0,s7=0;
#pragma unroll
        for (int oy = 0; oy < 2; ++oy) {
#pragma unroll
            for (int ox = 0; ox < 2; ++ox) {
                int yy = y0 + oy, xx = x0 + ox;
                float wgt = (oy ? fy : 1.f - fy) * (ox ? fx : 1.f - fx);
                if ((unsigned)yy < 256u && (unsigned)xx < 256u) {
                    const float* yp = yn + ((size_t)yy * 256 + xx) * 8;
                    float4 a  = *(const float4*)(yp + 0);
                    float4 c4 = *(const float4*)(yp + 4);
                    s0 = fmaf(wgt, a.x,  s0); s1 = fmaf(wgt, a.y,  s1);
                    s2 = fmaf(wgt, a.z,  s2); s3 = fmaf(wgt, a.w,  s3);
                    s4 = fmaf(wgt, c4.x, s4); s5 = fmaf(wgt, c4.y, s5);
                    s6 = fmaf(wgt, c4.z, s6); s7 = fmaf(wgt, c4.w, s7);
                }
            }
        }
        cp[0 * 9 + k] = m * s0; cp[1 * 9 + k] = m * s1;
        cp[2 * 9 + k] = m * s2; cp[3 * 9 + k] = m * s3;
        cp[4 * 9 + k] = m * s4; cp[5 * 9 + k] = m * s5;
        cp[6 * 9 + k] = m * s6; cp[7 * 9 + k] = m * s7;
    }
}

// ---------------- Kernel C: out[n][o][hw] = sum_j cols[pix][j] * Wd[o*72+j] ----------------
// Block: 64 pixels x 128 o-channels; thread: 4 pixels x 8 o.
__global__ __launch_bounds__(256) void k_gemm(const float* __restrict__ cols,
                                              const float* __restrict__ wd,
                                              float* __restrict__ out) {
    __shared__ float wS[128 * 72];     // [o_local][j]
    __shared__ float cS[72 * 64];      // [j][p] transposed
    int t = threadIdx.x;
    int ptile = blockIdx.x;            // 2048 tiles of 64 pixels
    int otile = blockIdx.y;            // 4 tiles of 128 o

    // load weight slice
    const float* wsrc = wd + (size_t)otile * 128 * 72;
    for (int i = t * 4; i < 128 * 72; i += 256 * 4) {
        *(float4*)(wS + i) = *(const float4*)(wsrc + i);
    }
    // load cols tile, transpose into cS[j][p]
    {
        int p = t & 63, jg = t >> 6;   // jg in 0..3
        const float* csrc = cols + ((size_t)ptile * 64 + p) * KJ;
        for (int g = jg; g < 18; g += 4) {
            float4 v = *(const float4*)(csrc + g * 4);
            cS[(g * 4 + 0) * 64 + p] = v.x;
            cS[(g * 4 + 1) * 64 + p] = v.y;
            cS[(g * 4 + 2) * 64 + p] = v.z;
            cS[(g * 4 + 3) * 64 + p] = v.w;
        }
    }
    __syncthreads();

    int pg = t & 15;                   // pixel group: 4 consecutive pixels
    int og = t >> 4;                   // o group: 8 o-channels
    float4 acc[8];
#pragma unroll
    for (int i = 0; i < 8; ++i) acc[i] = make_float4(0.f, 0.f, 0.f, 0.f);

#pragma unroll 6
    for (int jb = 0; jb < 72; jb += 4) {
        float4 cv0 = *(const float4*)(cS + (jb + 0) * 64 + pg * 4);
        float4 cv1 = *(const float4*)(cS + (jb + 1) * 64 + pg * 4);
        float4 cv2 = *(const float4*)(cS + (jb + 2) * 64 + pg * 4);
        float4 cv3 = *(const float4*)(cS + (jb + 3) * 64 + pg * 4);
#pragma unroll
        for (int i = 0; i < 8; ++i) {
            float4 w4 = *(const float4*)(wS + (og * 8 + i) * 72 + jb);
            acc[i].x = fmaf(w4.x, cv0.x, acc[i].x);
            acc[i].y = fmaf(w4.x, cv0.y, acc[i].y);
            acc[i].z = fmaf(w4.x, cv0.z, acc[i].z);
            acc[i].w = fmaf(w4.x, cv0.w, acc[i].w);
            acc[i].x = fmaf(w4.y, cv1.x, acc[i].x);
            acc[i].y = fmaf(w4.y, cv1.y, acc[i].y);
            acc[i].z = fmaf(w4.y, cv1.z, acc[i].z);
            acc[i].w = fmaf(w4.y, cv1.w, acc[i].w);
            acc[i].x = fmaf(w4.z, cv2.x, acc[i].x);
            acc[i].y = fmaf(w4.z, cv2.y, acc[i].y);
            acc[i].z = fmaf(w4.z, cv2.z, acc[i].z);
            acc[i].w = fmaf(w4.z, cv2.w, acc[i].w);
            acc[i].x = fmaf(w4.w, cv3.x, acc[i].x);
            acc[i].y = fmaf(w4.w, cv3.y, acc[i].y);
            acc[i].z = fmaf(w4.w, cv3.z, acc[i].z);
            acc[i].w = fmaf(w4.w, cv3.w, acc[i].w);
        }
    }

    int pix0 = ptile * 64;
    int n = pix0 >> 14;
    int hw = (pix0 & 16383) + pg * 4;
    float* op = out + (size_t)n * (OCN * 16384) + (size_t)(otile * 128 + og * 8) * 16384 + hw;
#pragma unroll
    for (int i = 0; i < 8; ++i) {
        *(float4*)(op + (size_t)i * 16384) = acc[i];
    }
}

extern "C" void kernel_launch(void* const* d_in, const int* in_sizes, int n_in,
                              void* d_out, int out_size, void* d_ws, size_t ws_size,
                              hipStream_t stream) {
    const float* x   = (const float*)d_in[0];
    const float* c1w = (const float*)d_in[1];
    const float* c1b = (const float*)d_in[2];
    const float* ow  = (const float*)d_in[3];
    const float* ob  = (const float*)d_in[4];
    const float* dw  = (const float*)d_in[5];
    float* out = (float*)d_out;

    float* y    = (float*)d_ws;                 // 8*256*256*8 = 4,194,304 floats (16.8 MB)
    float* cols = y + 4194304;                  // 8*128*128*72 = 9,437,184 floats (37.7 MB)

    hipLaunchKernelGGL(k_conv1, dim3(2048), dim3(256), 0, stream, x, c1w, c1b, y);
    hipLaunchKernelGGL(k_offset_sample, dim3(512), dim3(256), 0, stream, y, ow, ob, cols);
    hipLaunchKernelGGL(k_gemm, dim3(2048, 4), dim3(256), 0, stream, cols, dw, out);
}

// Round 5
// 342.542 us; speedup vs baseline: 1.6796x; 1.6796x over previous
//
#include <hip/hip_runtime.h>
#include <math.h>

// Problem constants
#define NB   8      // batch
#define HH   256
#define WW   256
#define CY   8      // y channels
#define HO   128
#define WO   128
#define OCN  512    // dcn output channels
#define K2   9
#define KJ   72     // 8*9 reduction length
#define KP   104    // padded cols row length (bf16): 72 real + zeros; 208B rows (16B-mult, 2-way-free LDS stride)

typedef short bf16x8 __attribute__((ext_vector_type(8)));
typedef float f32x4  __attribute__((ext_vector_type(4)));

static __device__ inline unsigned short f2bf(float f) {
    union { float f; unsigned u; } v; v.f = f;
    unsigned r = (v.u + 0x7FFFu + ((v.u >> 16) & 1u)) >> 16;   // RNE
    return (unsigned short)r;
}

// ---------------- Kernel A: y = leaky(conv1x1(x) + b), stored NHWC(8) ----------------
__global__ __launch_bounds__(256) void k_conv1(const float* __restrict__ x,
                                               const float* __restrict__ w,
                                               const float* __restrict__ b,
                                               float* __restrict__ y) {
    int idx = blockIdx.x * 256 + threadIdx.x;      // n*65536 + h*256 + w
    int n = idx >> 16, hw = idx & 65535;
    const float* xp = x + (size_t)n * 3 * 65536 + hw;
    float x0 = xp[0], x1 = xp[65536], x2 = xp[131072];
    float o[8];
#pragma unroll
    for (int oc = 0; oc < 8; ++oc) {
        float v = fmaf(w[oc*3+0], x0, fmaf(w[oc*3+1], x1, fmaf(w[oc*3+2], x2, b[oc])));
        o[oc] = v >= 0.f ? v : 0.1f * v;
    }
    float* yp = y + (size_t)idx * 8;
    *(float4*)(yp + 0) = make_float4(o[0], o[1], o[2], o[3]);
    *(float4*)(yp + 4) = make_float4(o[4], o[5], o[6], o[7]);
}

// ---------------- Kernel D: pad/convert dcn_w fp32[512][72] -> bf16[512][104] ----------------
__global__ __launch_bounds__(256) void k_wpad(const float* __restrict__ wd,
                                              unsigned short* __restrict__ wdb) {
    int i = blockIdx.x * 256 + threadIdx.x;        // exactly 208*256 = 53248 = 512*104
    int row = i / KP;
    int k = i - row * KP;
    float v = (k < KJ) ? wd[row * KJ + k] : 0.f;
    wdb[i] = f2bf(v);
}

// ---- Kernel B: offset conv (27ch, 3x3, s2, p1) + sigmoid mask + bilinear sample ----
// Writes cols as bf16 [pix][104], j = c*9+k, k>=72 zero. Coalesced via LDS stage.
__global__ __launch_bounds__(256) void k_offset_sample(const float* __restrict__ y,
                                                       const float* __restrict__ ow,
                                                       const float* __restrict__ ob,
                                                       unsigned short* __restrict__ cols) {
    // union: conv weights during compute, then 256x208B stage buffer
    __shared__ __align__(16) unsigned char smem[256 * 2 * KP];   // 53248 B
    float* wT = (float*)smem;                 // [9][27][8] -> 1944 floats
    float* bS = (float*)smem + 1944;          // 27 floats
    unsigned short* stage = (unsigned short*)smem;  // [256][104]

    int t = threadIdx.x;
    for (int i = t; i < 1944; i += 256) {
        int oc = i / 72, rem = i - oc * 72;
        int c = rem / 9, pos = rem - c * 9;
        wT[pos * 216 + oc * 8 + c] = ow[i];
    }
    if (t < 27) bS[t] = ob[t];
    __syncthreads();

    int idx = blockIdx.x * 256 + t;                // n*16384 + ho*128 + wo
    int n = idx >> 14, hw = idx & 16383;
    int ho = hw >> 7, wo = hw & 127;
    const float* yn = y + (size_t)n * (HH * WW * CY);

    float acc[27];
#pragma unroll
    for (int oc = 0; oc < 27; ++oc) acc[oc] = bS[oc];

#pragma unroll
    for (int pos = 0; pos < 9; ++pos) {
        int kh = pos / 3, kw = pos - kh * 3;
        int hi = 2 * ho - 1 + kh, wi = 2 * wo - 1 + kw;
        if ((unsigned)hi < 256u && (unsigned)wi < 256u) {
            const float* yp = yn + ((size_t)hi * 256 + wi) * 8;
            float4 a  = *(const float4*)(yp + 0);
            float4 c4 = *(const float4*)(yp + 4);
#pragma unroll
            for (int oc = 0; oc < 27; ++oc) {
                float4 w0 = *(const float4*)(wT + pos * 216 + oc * 8 + 0);
                float4 w1 = *(const float4*)(wT + pos * 216 + oc * 8 + 4);
                acc[oc] += w0.x * a.x + w0.y * a.y + w0.z * a.z + w0.w * a.w
                         + w1.x * c4.x + w1.y * c4.y + w1.z * c4.z + w1.w * c4.w;
            }
        }
    }
    // all threads done reading wT before stage overwrites it
    __syncthreads();

#pragma unroll
    for (int k = 0; k < 9; ++k) {
        float dy = acc[2 * k], dx = acc[2 * k + 1];
        float m  = 1.f / (1.f + expf(-acc[18 + k]));
        float py = (float)(2 * ho - 1 + (k / 3)) + dy;
        float px = (float)(2 * wo - 1 + (k % 3)) + dx;
        float y0f = floorf(py), x0f = floorf(px);
        float fy = py - y0f, fx = px - x0f;
        int y0 = (int)y0f, x0 = (int)x0f;
        float s0=0,s1=0,s2=0,s3=0,s4=0,s5=0,s6=0,s7=0;
#pragma unroll
        for (int oy = 0; oy < 2; ++oy) {
#pragma unroll
            for (int ox = 0; ox < 2; ++ox) {
                int yy = y0 + oy, xx = x0 + ox;
                float wgt = (oy ? fy : 1.f - fy) * (ox ? fx : 1.f - fx);
                if ((unsigned)yy < 256u && (unsigned)xx < 256u) {
                    const float* yp = yn + ((size_t)yy * 256 + xx) * 8;
                    float4 a  = *(const float4*)(yp + 0);
                    float4 c4 = *(const float4*)(yp + 4);
                    s0 = fmaf(wgt, a.x,  s0); s1 = fmaf(wgt, a.y,  s1);
                    s2 = fmaf(wgt, a.z,  s2); s3 = fmaf(wgt, a.w,  s3);
                    s4 = fmaf(wgt, c4.x, s4); s5 = fmaf(wgt, c4.y, s5);
                    s6 = fmaf(wgt, c4.z, s6); s7 = fmaf(wgt, c4.w, s7);
                }
            }
        }
        unsigned short* sp = stage + t * KP + k;
        sp[0*9] = f2bf(m*s0); sp[1*9] = f2bf(m*s1); sp[2*9] = f2bf(m*s2); sp[3*9] = f2bf(m*s3);
        sp[4*9] = f2bf(m*s4); sp[5*9] = f2bf(m*s5); sp[6*9] = f2bf(m*s6); sp[7*9] = f2bf(m*s7);
    }
    // zero pad k = 72..103 (bytes 144..207 of the row)
    {
        uint4 z; z.x = z.y = z.z = z.w = 0u;
        uint4* zp = (uint4*)((unsigned char*)smem + (size_t)t * 2 * KP + 144);
        zp[0] = z; zp[1] = z; zp[2] = z; zp[3] = z;
    }
    __syncthreads();
    // coalesced flat copy: 256*208B = 3328 uint4 chunks, 13 full iterations
    const uint4* sL = (const uint4*)smem;
    uint4* gD = (uint4*)(cols + (size_t)blockIdx.x * 256 * KP);
#pragma unroll
    for (int i = 0; i < 13; ++i) {
        int c = t + i * 256;
        gD[c] = sL[c];
    }
}

// ---------------- Kernel C: MFMA GEMM  D[oc][pix] = sum_k W[oc][k] * cols[pix][k] ----------------
// Block: 128 oc (M) x 128 pix (N), 4 waves; wave w owns oc rows [w*32, w*32+32).
// K = 96 (padded), 3 steps of 32. A = wdb (global, L2-hot), B = cols tile (LDS).
__global__ __launch_bounds__(256) void k_gemm_mfma(const unsigned short* __restrict__ colsb,
                                                   const unsigned short* __restrict__ wdb,
                                                   float* __restrict__ out) {
    __shared__ __align__(16) unsigned short cT[128 * KP];   // 26624 B
    int t = threadIdx.x;
    int pixtile = blockIdx.x;      // 1024 tiles of 128 pixels
    int octile  = blockIdx.y;      // 4 tiles of 128 oc

    // stage cols tile: flat contiguous 1664 uint4 chunks
    {
        const uint4* g4 = (const uint4*)(colsb + (size_t)pixtile * 128 * KP);
        uint4* l4 = (uint4*)cT;
#pragma unroll
        for (int i = 0; i < 7; ++i) {
            int c = t + i * 256;
            if (c < 1664) l4[c] = g4[c];
        }
    }

    int wave = t >> 6, lane = t & 63;
    int lr = lane & 15, lk = lane >> 4;
    int ocb = octile * 128 + wave * 32;

    // A fragments from global (independent of LDS staging): lane holds W[ocb+m*16+lr][kk*32+lk*8 .. +7]
    bf16x8 aF[2][3];
#pragma unroll
    for (int m = 0; m < 2; ++m)
#pragma unroll
        for (int kk = 0; kk < 3; ++kk)
            aF[m][kk] = *(const bf16x8*)(wdb + (size_t)(ocb + m * 16 + lr) * KP + kk * 32 + lk * 8);

    __syncthreads();

    f32x4 acc[2][8];
#pragma unroll
    for (int m = 0; m < 2; ++m)
#pragma unroll
        for (int n = 0; n < 8; ++n) acc[m][n] = (f32x4){0.f, 0.f, 0.f, 0.f};

#pragma unroll
    for (int kk = 0; kk < 3; ++kk) {
        bf16x8 bF[8];
#pragma unroll
        for (int n = 0; n < 8; ++n)
            bF[n] = *(const bf16x8*)(cT + (n * 16 + lr) * KP + kk * 32 + lk * 8);
#pragma unroll
        for (int n = 0; n < 8; ++n)
#pragma unroll
            for (int m = 0; m < 2; ++m)
                acc[m][n] = __builtin_amdgcn_mfma_f32_16x16x32_bf16(aF[m][kk], bF[n], acc[m][n], 0, 0, 0);
    }

    // store: D col = lane&15 = pixel (coalesced 64B lines), row = lk*4+reg = oc
    int pix0 = pixtile * 128;
    int nimg = pix0 >> 14;
    int hwbase = pix0 & 16383;
#pragma unroll
    for (int m = 0; m < 2; ++m) {
        int oc = ocb + m * 16 + lk * 4;
#pragma unroll
        for (int n = 0; n < 8; ++n) {
            int hw = hwbase + n * 16 + lr;
            float* op = out + ((size_t)nimg * OCN + oc) * 16384 + hw;
            op[0]         = acc[m][n][0];
            op[16384]     = acc[m][n][1];
            op[2 * 16384] = acc[m][n][2];
            op[3 * 16384] = acc[m][n][3];
        }
    }
}

extern "C" void kernel_launch(void* const* d_in, const int* in_sizes, int n_in,
                              void* d_out, int out_size, void* d_ws, size_t ws_size,
                              hipStream_t stream) {
    const float* x   = (const float*)d_in[0];
    const float* c1w = (const float*)d_in[1];
    const float* c1b = (const float*)d_in[2];
    const float* ow  = (const float*)d_in[3];
    const float* ob  = (const float*)d_in[4];
    const float* dw  = (const float*)d_in[5];
    float* out = (float*)d_out;

    // ws layout:
    //   y     fp32  8*256*256*8            = 16,777,216 B
    //   colsb bf16  131072*104*2           = 27,262,976 B
    //   wdb   bf16  512*104*2              =    106,496 B      total ~44.1 MB
    float* y = (float*)d_ws;
    unsigned short* colsb = (unsigned short*)((unsigned char*)d_ws + 16777216);
    unsigned short* wdb   = (unsigned short*)((unsigned char*)d_ws + 16777216 + 27262976);

    hipLaunchKernelGGL(k_conv1, dim3(2048), dim3(256), 0, stream, x, c1w, c1b, y);
    hipLaunchKernelGGL(k_wpad, dim3(208), dim3(256), 0, stream, dw, wdb);
    hipLaunchKernelGGL(k_offset_sample, dim3(512), dim3(256), 0, stream, y, ow, ob, colsb);
    hipLaunchKernelGGL(k_gemm_mfma, dim3(1024, 4), dim3(256), 0, stream, colsb, wdb, out);
}

// Round 6
// 335.331 us; speedup vs baseline: 1.7157x; 1.0215x over previous
//
#include <hip/hip_runtime.h>
#include <math.h>

// Problem constants
#define NB   8      // batch
#define HH   256
#define WW   256
#define CY   8      // y channels
#define HO   128
#define WO   128
#define OCN  512    // dcn output channels
#define K2   9
#define KJ   72     // 8*9 reduction length
#define KP   104    // padded cols row length (bf16): 72 real + zeros; 208B rows

typedef short bf16x8 __attribute__((ext_vector_type(8)));
typedef float f32x4  __attribute__((ext_vector_type(4)));

static __device__ inline unsigned short f2bf(float f) {
    union { float f; unsigned u; } v; v.f = f;
    unsigned r = (v.u + 0x7FFFu + ((v.u >> 16) & 1u)) >> 16;   // RNE
    return (unsigned short)r;
}

// ---------------- Kernel A: y = leaky(conv1x1(x) + b), stored NHWC(8) ----------------
__global__ __launch_bounds__(256) void k_conv1(const float* __restrict__ x,
                                               const float* __restrict__ w,
                                               const float* __restrict__ b,
                                               float* __restrict__ y) {
    int idx = blockIdx.x * 256 + threadIdx.x;      // n*65536 + h*256 + w
    int n = idx >> 16, hw = idx & 65535;
    const float* xp = x + (size_t)n * 3 * 65536 + hw;
    float x0 = xp[0], x1 = xp[65536], x2 = xp[131072];
    float o[8];
#pragma unroll
    for (int oc = 0; oc < 8; ++oc) {
        float v = fmaf(w[oc*3+0], x0, fmaf(w[oc*3+1], x1, fmaf(w[oc*3+2], x2, b[oc])));
        o[oc] = v >= 0.f ? v : 0.1f * v;
    }
    float* yp = y + (size_t)idx * 8;
    *(float4*)(yp + 0) = make_float4(o[0], o[1], o[2], o[3]);
    *(float4*)(yp + 4) = make_float4(o[4], o[5], o[6], o[7]);
}

// ---------------- Kernel D: pad/convert dcn_w fp32[512][72] -> bf16[512][104] ----------------
__global__ __launch_bounds__(256) void k_wpad(const float* __restrict__ wd,
                                              unsigned short* __restrict__ wdb) {
    int i = blockIdx.x * 256 + threadIdx.x;        // exactly 208*256 = 53248 = 512*104
    int row = i / KP;
    int k = i - row * KP;
    float v = (k < KJ) ? wd[row * KJ + k] : 0.f;
    wdb[i] = f2bf(v);
}

// ---- Kernel B: offset conv (27ch, 3x3, s2, p1) + sigmoid mask + bilinear sample ----
// Weights fetched via wave-uniform indices -> scalar loads (SGPR operands), no LDS for weights.
// Writes cols as bf16 [pix][104], j = c*9+k, k>=72 zero. Coalesced via LDS stage.
__global__ __launch_bounds__(256) void k_offset_sample(const float* __restrict__ y,
                                                       const float* __restrict__ ow,
                                                       const float* __restrict__ ob,
                                                       unsigned short* __restrict__ cols) {
    __shared__ __align__(16) unsigned short stage[256 * KP];   // 53248 B

    int t = threadIdx.x;
    int idx = blockIdx.x * 256 + t;                // n*16384 + ho*128 + wo
    int n = idx >> 14, hw = idx & 16383;
    int ho = hw >> 7, wo = hw & 127;
    const float* yn = y + (size_t)n * (HH * WW * CY);

    float acc[27];
#pragma unroll
    for (int oc = 0; oc < 27; ++oc) acc[oc] = ob[oc];   // uniform -> s_load

    // offset conv: 9 taps, weights wave-uniform (scalar pipe), pixels in VGPRs
#pragma unroll 1
    for (int pos = 0; pos < 9; ++pos) {
        int kh = pos / 3, kw = pos - kh * 3;
        int hi = 2 * ho - 1 + kh, wi = 2 * wo - 1 + kw;
        float4 a  = make_float4(0.f, 0.f, 0.f, 0.f);
        float4 c4 = make_float4(0.f, 0.f, 0.f, 0.f);
        if ((unsigned)hi < 256u && (unsigned)wi < 256u) {
            const float* yp = yn + ((size_t)hi * 256 + wi) * 8;
            a  = *(const float4*)(yp + 0);
            c4 = *(const float4*)(yp + 4);
        }
        const float* wp = ow + pos;                // + oc*72 + c*9 (uniform)
#pragma unroll
        for (int oc = 0; oc < 27; ++oc) {
            float s = fmaf(wp[oc*72 + 0*9], a.x,
                      fmaf(wp[oc*72 + 1*9], a.y,
                      fmaf(wp[oc*72 + 2*9], a.z,
                      fmaf(wp[oc*72 + 3*9], a.w,
                      fmaf(wp[oc*72 + 4*9], c4.x,
                      fmaf(wp[oc*72 + 5*9], c4.y,
                      fmaf(wp[oc*72 + 6*9], c4.z,
                           wp[oc*72 + 7*9] * c4.w)))))));
            acc[oc] += s;
        }
    }

    // bilinear sampling + mask, write bf16 rows into LDS stage
#pragma unroll
    for (int k = 0; k < 9; ++k) {
        float dy = acc[2 * k], dx = acc[2 * k + 1];
        float m  = 1.f / (1.f + expf(-acc[18 + k]));
        float py = (float)(2 * ho - 1 + (k / 3)) + dy;
        float px = (float)(2 * wo - 1 + (k % 3)) + dx;
        float y0f = floorf(py), x0f = floorf(px);
        float fy = py - y0f, fx = px - x0f;
        int y0 = (int)y0f, x0 = (int)x0f;
        float s0=0,s1=0,s2=0,s3=0,s4=0,s5=0,s6=0,s7=0;
#pragma unroll
        for (int oy = 0; oy < 2; ++oy) {
#pragma unroll
            for (int ox = 0; ox < 2; ++ox) {
                int yy = y0 + oy, xx = x0 + ox;
                float wgt = (oy ? fy : 1.f - fy) * (ox ? fx : 1.f - fx);
                if ((unsigned)yy < 256u && (unsigned)xx < 256u) {
                    const float* yp = yn + ((size_t)yy * 256 + xx) * 8;
                    float4 a  = *(const float4*)(yp + 0);
                    float4 c4 = *(const float4*)(yp + 4);
                    s0 = fmaf(wgt, a.x,  s0); s1 = fmaf(wgt, a.y,  s1);
                    s2 = fmaf(wgt, a.z,  s2); s3 = fmaf(wgt, a.w,  s3);
                    s4 = fmaf(wgt, c4.x, s4); s5 = fmaf(wgt, c4.y, s5);
                    s6 = fmaf(wgt, c4.z, s6); s7 = fmaf(wgt, c4.w, s7);
                }
            }
        }
        unsigned short* sp = stage + t * KP + k;
        sp[0*9] = f2bf(m*s0); sp[1*9] = f2bf(m*s1); sp[2*9] = f2bf(m*s2); sp[3*9] = f2bf(m*s3);
        sp[4*9] = f2bf(m*s4); sp[5*9] = f2bf(m*s5); sp[6*9] = f2bf(m*s6); sp[7*9] = f2bf(m*s7);
    }
    // zero pad k = 72..103 (bytes 144..207 of the row)
    {
        uint4 z; z.x = z.y = z.z = z.w = 0u;
        uint4* zp = (uint4*)((unsigned char*)stage + (size_t)t * 2 * KP + 144);
        zp[0] = z; zp[1] = z; zp[2] = z; zp[3] = z;
    }
    __syncthreads();
    // coalesced flat copy: 256*208B = 3328 uint4 chunks, 13 full iterations
    const uint4* sL = (const uint4*)stage;
    uint4* gD = (uint4*)(cols + (size_t)blockIdx.x * 256 * KP);
#pragma unroll
    for (int i = 0; i < 13; ++i) {
        int c = t + i * 256;
        gD[c] = sL[c];
    }
}

// ---------------- Kernel C: MFMA GEMM  D[oc][pix] = sum_k W[oc][k] * cols[pix][k] ----------------
// Block: 128 oc (M) x 128 pix (N), 4 waves; wave w owns oc rows [w*32, w*32+32).
// K = 96 (padded), 3 steps of 32. A = wdb (global, L2-hot), B = cols tile (LDS).
__global__ __launch_bounds__(256) void k_gemm_mfma(const unsigned short* __restrict__ colsb,
                                                   const unsigned short* __restrict__ wdb,
                                                   float* __restrict__ out) {
    __shared__ __align__(16) unsigned short cT[128 * KP];   // 26624 B
    int t = threadIdx.x;
    int pixtile = blockIdx.x;      // 1024 tiles of 128 pixels
    int octile  = blockIdx.y;      // 4 tiles of 128 oc

    // stage cols tile: flat contiguous 1664 uint4 chunks
    {
        const uint4* g4 = (const uint4*)(colsb + (size_t)pixtile * 128 * KP);
        uint4* l4 = (uint4*)cT;
#pragma unroll
        for (int i = 0; i < 7; ++i) {
            int c = t + i * 256;
            if (c < 1664) l4[c] = g4[c];
        }
    }

    int wave = t >> 6, lane = t & 63;
    int lr = lane & 15, lk = lane >> 4;
    int ocb = octile * 128 + wave * 32;

    // A fragments from global (independent of LDS staging): lane holds W[ocb+m*16+lr][kk*32+lk*8 .. +7]
    bf16x8 aF[2][3];
#pragma unroll
    for (int m = 0; m < 2; ++m)
#pragma unroll
        for (int kk = 0; kk < 3; ++kk)
            aF[m][kk] = *(const bf16x8*)(wdb + (size_t)(ocb + m * 16 + lr) * KP + kk * 32 + lk * 8);

    __syncthreads();

    f32x4 acc[2][8];
#pragma unroll
    for (int m = 0; m < 2; ++m)
#pragma unroll
        for (int n = 0; n < 8; ++n) acc[m][n] = (f32x4){0.f, 0.f, 0.f, 0.f};

#pragma unroll
    for (int kk = 0; kk < 3; ++kk) {
        bf16x8 bF[8];
#pragma unroll
        for (int n = 0; n < 8; ++n)
            bF[n] = *(const bf16x8*)(cT + (n * 16 + lr) * KP + kk * 32 + lk * 8);
#pragma unroll
        for (int n = 0; n < 8; ++n)
#pragma unroll
            for (int m = 0; m < 2; ++m)
                acc[m][n] = __builtin_amdgcn_mfma_f32_16x16x32_bf16(aF[m][kk], bF[n], acc[m][n], 0, 0, 0);
    }

    // store: D col = lane&15 = pixel (coalesced 64B lines), row = lk*4+reg = oc
    int pix0 = pixtile * 128;
    int nimg = pix0 >> 14;
    int hwbase = pix0 & 16383;
#pragma unroll
    for (int m = 0; m < 2; ++m) {
        int oc = ocb + m * 16 + lk * 4;
#pragma unroll
        for (int n = 0; n < 8; ++n) {
            int hw = hwbase + n * 16 + lr;
            float* op = out + ((size_t)nimg * OCN + oc) * 16384 + hw;
            op[0]         = acc[m][n][0];
            op[16384]     = acc[m][n][1];
            op[2 * 16384] = acc[m][n][2];
            op[3 * 16384] = acc[m][n][3];
        }
    }
}

extern "C" void kernel_launch(void* const* d_in, const int* in_sizes, int n_in,
                              void* d_out, int out_size, void* d_ws, size_t ws_size,
                              hipStream_t stream) {
    const float* x   = (const float*)d_in[0];
    const float* c1w = (const float*)d_in[1];
    const float* c1b = (const float*)d_in[2];
    const float* ow  = (const float*)d_in[3];
    const float* ob  = (const float*)d_in[4];
    const float* dw  = (const float*)d_in[5];
    float* out = (float*)d_out;

    // ws layout:
    //   y     fp32  8*256*256*8            = 16,777,216 B
    //   colsb bf16  131072*104*2           = 27,262,976 B
    //   wdb   bf16  512*104*2              =    106,496 B      total ~44.1 MB
    float* y = (float*)d_ws;
    unsigned short* colsb = (unsigned short*)((unsigned char*)d_ws + 16777216);
    unsigned short* wdb   = (unsigned short*)((unsigned char*)d_ws + 16777216 + 27262976);

    hipLaunchKernelGGL(k_conv1, dim3(2048), dim3(256), 0, stream, x, c1w, c1b, y);
    hipLaunchKernelGGL(k_wpad, dim3(208), dim3(256), 0, stream, dw, wdb);
    hipLaunchKernelGGL(k_offset_sample, dim3(512), dim3(256), 0, stream, y, ow, ob, colsb);
    hipLaunchKernelGGL(k_gemm_mfma, dim3(1024, 4), dim3(256), 0, stream, colsb, wdb, out);
}